// Round 1
// baseline (125.774 us; speedup 1.0000x reference)
//
#include <hip/hip_runtime.h>

// DiffKS: x[b,t] = y[b,t] + sum_{k=0}^{N-1} A[b,t,k] * y_padded[b, t + N-1-k]
// y_padded = [reverse(zi), y]  (length N + T per batch)
// Pure FIR (no recurrence) -> fully parallel, memory-bound on A (602 MB).

#define NCOEF 588
#define TILE 8                    // t-values per block, one per wave
#define BLOCK (TILE * 64)         // 512 threads = 8 waves
#define WIN (NCOEF + TILE)        // staged y_padded window: 596 floats
#define PHLEN 152                 // per-phase length (>= ceil(WIN/4)=149), pad to kill write conflicts

__global__ __launch_bounds__(BLOCK) void diffks_kernel(
    const float* __restrict__ y,    // [B][T]
    const float* __restrict__ A,    // [B][T][NCOEF]
    const float* __restrict__ zi,   // [B][NCOEF]
    float* __restrict__ out,        // [B][T]
    int T)
{
    // y_padded window deinterleaved by (index & 3) so that the 4 taps of a
    // float4-A iteration each hit stride-1 LDS addresses across lanes
    // (conflict-free) instead of stride-4 (8-way conflict).
    __shared__ float sy4[4][PHLEN];

    const int blocksPerBatch = T / TILE;
    const int b  = blockIdx.x / blocksPerBatch;
    const int t0 = (blockIdx.x - b * blocksPerBatch) * TILE;

    const float* yb  = y  + (size_t)b * T;
    const float* zib = zi + (size_t)b * NCOEF;

    // Stage y_padded[b, t0 .. t0+WIN-1]; y_padded[j] = j<N ? zi[N-1-j] : y[j-N]
    for (int j = threadIdx.x; j < WIN; j += BLOCK) {
        const int jg = t0 + j;
        const float v = (jg < NCOEF) ? zib[NCOEF - 1 - jg] : yb[jg - NCOEF];
        sy4[j & 3][j >> 2] = v;
    }
    __syncthreads();

    const int w    = threadIdx.x >> 6;   // wave id -> which t in the tile
    const int lane = threadIdx.x & 63;
    const int t    = t0 + w;
    const float* Arow = A + ((size_t)b * T + t) * NCOEF;

    float acc = 0.f;
    const int base = w + NCOEF - 1;      // y_padded window index for k=0
    #pragma unroll
    for (int it = 0; it < 3; ++it) {
        const int k4 = lane + it * 64;   // float4 index; NCOEF/4 = 147
        if (k4 < NCOEF / 4) {
            const float4 a = *reinterpret_cast<const float4*>(Arow + 4 * k4);
            const int j0 = base - 4 * k4;
            acc += a.x * sy4[ j0      & 3][ j0      >> 2];
            acc += a.y * sy4[(j0 - 1) & 3][(j0 - 1) >> 2];
            acc += a.z * sy4[(j0 - 2) & 3][(j0 - 2) >> 2];
            acc += a.w * sy4[(j0 - 3) & 3][(j0 - 3) >> 2];
        }
    }

    // 64-lane wave reduction
    #pragma unroll
    for (int off = 32; off > 0; off >>= 1)
        acc += __shfl_down(acc, off, 64);

    if (lane == 0) {
        const int jy = w + NCOEF;        // y[b,t] = y_padded[t+N] (in window)
        out[(size_t)b * T + t] = sy4[jy & 3][jy >> 2] + acc;
    }
}

extern "C" void kernel_launch(void* const* d_in, const int* in_sizes, int n_in,
                              void* d_out, int out_size, void* d_ws, size_t ws_size,
                              hipStream_t stream) {
    const float* y  = (const float*)d_in[0];
    const float* A  = (const float*)d_in[1];
    const float* zi = (const float*)d_in[2];
    float* out = (float*)d_out;

    const int Bsz = in_sizes[2] / NCOEF;     // 4
    const int T   = in_sizes[0] / Bsz;       // 64000 (divisible by TILE=8)

    const int grid = Bsz * (T / TILE);       // 32000 blocks
    diffks_kernel<<<grid, BLOCK, 0, stream>>>(y, A, zi, out, T);
}

// Round 3
// 96.453 us; speedup vs baseline: 1.3040x; 1.3040x over previous
//
#include <hip/hip_runtime.h>

// DiffKS: x[b,t] = y[b,t] + sum_{k=0}^{N-1} A[b,t,k] * y_padded[b, t + N-1-k]
// y_padded = [reverse(zi), y].  Pure FIR, memory-bound on A (602 MB read-once).
// R1: chunked blocks (64 t / block), per-wave software pipeline over 8 t's.
// R2: fix — use clang ext_vector_type for __builtin_nontemporal_load
//     (HIP float4 is a class type the builtin rejects).

#define NCOEF 588
#define K4CNT (NCOEF / 4)          // 147 float4 per row
#define NW 8                       // waves per block
#define BLOCK (NW * 64)            // 512 threads
#define NITER 8                    // t's per wave
#define TTOT (NW * NITER)          // 64 t's per block
#define WIN (NCOEF + TTOT)         // 652: taps for all t + y[t] values
#define PH ((WIN + 3) / 4 + 1)     // 164 per deinterleave plane

typedef float f32x4 __attribute__((ext_vector_type(4)));

#define SY(j) sy4[(j) & 3][(j) >> 2]

__global__ __launch_bounds__(BLOCK) void diffks_kernel(
    const float* __restrict__ y,    // [B][T]
    const float* __restrict__ A,    // [B][T][NCOEF]
    const float* __restrict__ zi,   // [B][NCOEF]
    float* __restrict__ out,        // [B][T]
    int T)
{
    // y_padded window deinterleaved by (index & 3): the 4 taps of one float4-A
    // chunk read stride-1 descending LDS addresses across lanes (2-way = free).
    __shared__ float sy4[4][PH];

    const int blocksPerBatch = T / TTOT;
    const int b  = blockIdx.x / blocksPerBatch;
    const int t0 = (blockIdx.x - b * blocksPerBatch) * TTOT;

    const float* yb  = y  + (size_t)b * T;
    const float* zib = zi + (size_t)b * NCOEF;

    // Stage y_padded[b, t0 .. t0+WIN-1]; y_padded[j] = j<N ? zi[N-1-j] : y[j-N]
    for (int j = threadIdx.x; j < WIN; j += BLOCK) {
        const int jg = t0 + j;
        const float v = (jg < NCOEF) ? zib[NCOEF - 1 - jg] : yb[jg - NCOEF];
        SY(j) = v;
    }
    __syncthreads();

    const int w    = threadIdx.x >> 6;   // wave id
    const int lane = threadIdx.x & 63;
    const int k40 = lane;                // float4 index, iter 0
    const int k41 = lane + 64;           // iter 1
    const int k42 = lane + 128;          // iter 2 (only lanes 0..18 active)
    const bool act2 = (k42 < K4CNT);

    const float* Abase = A + ((size_t)b * T + t0) * NCOEF;
    const size_t bT = (size_t)b * T + t0;

    // prefetch t-local = w (i = 0)
    const float* Ar0 = Abase + (size_t)w * NCOEF;
    f32x4 c0 = __builtin_nontemporal_load((const f32x4*)(Ar0 + 4 * k40));
    f32x4 c1 = __builtin_nontemporal_load((const f32x4*)(Ar0 + 4 * k41));
    f32x4 c2 = (f32x4)(0.f);
    if (act2) c2 = __builtin_nontemporal_load((const f32x4*)(Ar0 + 4 * k42));

    #pragma unroll
    for (int i = 0; i < NITER; ++i) {
        const int tl = i * NW + w;       // local t in [0, TTOT)

        // software pipeline: issue next t's loads before current reduce
        f32x4 n0 = c0, n1 = c1, n2 = c2;
        if (i + 1 < NITER) {
            const float* An = Abase + (size_t)(tl + NW) * NCOEF;
            n0 = __builtin_nontemporal_load((const f32x4*)(An + 4 * k40));
            n1 = __builtin_nontemporal_load((const f32x4*)(An + 4 * k41));
            if (act2) n2 = __builtin_nontemporal_load((const f32x4*)(An + 4 * k42));
        }

        const int base = tl + NCOEF - 1;
        float acc;
        {
            const int j0 = base - 4 * k40;
            acc  = c0.x * SY(j0);
            acc += c0.y * SY(j0 - 1);
            acc += c0.z * SY(j0 - 2);
            acc += c0.w * SY(j0 - 3);
        }
        {
            const int j0 = base - 4 * k41;
            acc += c1.x * SY(j0);
            acc += c1.y * SY(j0 - 1);
            acc += c1.z * SY(j0 - 2);
            acc += c1.w * SY(j0 - 3);
        }
        if (act2) {
            const int j0 = base - 4 * k42;
            acc += c2.x * SY(j0);
            acc += c2.y * SY(j0 - 1);
            acc += c2.z * SY(j0 - 2);
            acc += c2.w * SY(j0 - 3);
        }

        // 64-lane wave reduction
        #pragma unroll
        for (int off = 32; off > 0; off >>= 1)
            acc += __shfl_down(acc, off, 64);

        if (lane == 0)
            out[bT + tl] = SY(tl + NCOEF) + acc;

        c0 = n0; c1 = n1; c2 = n2;
    }
}

extern "C" void kernel_launch(void* const* d_in, const int* in_sizes, int n_in,
                              void* d_out, int out_size, void* d_ws, size_t ws_size,
                              hipStream_t stream) {
    const float* y  = (const float*)d_in[0];
    const float* A  = (const float*)d_in[1];
    const float* zi = (const float*)d_in[2];
    float* out = (float*)d_out;

    const int Bsz = in_sizes[2] / NCOEF;     // 4
    const int T   = in_sizes[0] / Bsz;       // 64000 (divisible by TTOT=64)

    const int grid = Bsz * (T / TTOT);       // 4000 blocks
    diffks_kernel<<<grid, BLOCK, 0, stream>>>(y, A, zi, out, T);
}